// Round 12
// baseline (147.428 us; speedup 1.0000x reference)
//
#include <hip/hip_runtime.h>

// Path signature, depth 4, D=8. Output layout (matches JAX flatten):
//   s1[8] | s2[64] (i*8+j) | s3[512] (i*64+j*8+k) | s4[4096] (i*512+j*64+k*8+l)
//
// TWO kernels, ONE dependency edge (rounds 7-11 pinned 3-kernel trees at
// ~28.4us regardless of fold count => ~9us/edge fixed cost dominates):
//   k1: 64 blocks x 256 thr, each computes the signature of its ~128-increment
//       chunk (state fully thread-private in registers, barrier-free scan).
//   k2: ONE block x 1024 thr = 4 independent 256-thread fold engines.
//       All 64 partials' lower levels staged into 151.5KB LDS once; engine e
//       reg-accumulates sigs [16e,16e+16) (15 folds, engines concurrent on the
//       4 SIMDs); engines 1-3 publish to g2 (global, same-CU visibility after
//       __syncthreads vmcnt drain); engine 0 folds the 3 results -> out.
//       Serial folds 15+3=18 vs R11's 14, but one edge (-9us) removed.
// Fold engine (validated rounds 6-11): 2-deep q4 register double-buffer,
// runtime fold loop (live-set control; 4-deep ring + full unroll spilled in
// round 4: VGPR=256, +10MB scratch writes, 3x slower). 1024-thr block caps
// VGPR at 128 — engine live set ~100, should fit without spill.
#define SIGLEN 4680
#define S1OFF 0
#define S2OFF 8
#define S3OFF 72
#define S4OFF 584
#define NCHUNK 64
#define MAXLEN 128
#define LROW 592  // LDS floats per staged sig (584 + 8 pad)

struct SigRegs { float s4[16]; float a1, a2, a30, a31; };

// s3 chunk swizzle: float4 chunk c (0..127) lives at float-offset
// S3OFF + 4*(c ^ ((c>>4)&7)). Involution, bijective, 16B-aligned. Makes the
// 16*(t&31)-pattern b128 reads 4-way instead of 16-way conflicted.
__device__ __forceinline__ int s3off(int c) {
  return S3OFF + 4 * (c ^ ((c >> 4) & 7));
}

__device__ __forceinline__ void load_sig(SigRegs& A, const float* __restrict__ B,
                                         int i_idx, int t) {
  const float4* p4 = (const float4*)(B + S4OFF + 16 * t);
#pragma unroll
  for (int r = 0; r < 4; ++r) {
    const float4 v = p4[r];
    A.s4[4 * r] = v.x; A.s4[4 * r + 1] = v.y; A.s4[4 * r + 2] = v.z; A.s4[4 * r + 3] = v.w;
  }
  A.a1 = B[S1OFF + i_idx];
  A.a2 = B[S2OFF + (t >> 2)];
  const float2 a3i = *(const float2*)(B + S3OFF + 2 * t);
  A.a30 = a3i.x; A.a31 = a3i.y;
}

__device__ __forceinline__ void store_sig(const SigRegs& A, float* __restrict__ o,
                                          int i_idx, int t) {
  if ((t & 31) == 0) o[S1OFF + i_idx] = A.a1;
  if ((t & 3) == 0) o[S2OFF + (t >> 2)] = A.a2;
  *(float2*)(o + S3OFF + 2 * t) = make_float2(A.a30, A.a31);
  float4* o4 = (float4*)(o + S4OFF + 16 * t);
#pragma unroll
  for (int r = 0; r < 4; ++r)
    o4[r] = make_float4(A.s4[4 * r], A.s4[4 * r + 1], A.s4[4 * r + 2], A.s4[4 * r + 3]);
}

// Chen left-fold A <- A*B; B lower levels from LDS row R, B.s4 own-slice from
// registers q4. Math identical to the verified round-2 kernel:
//   c4 = a4 + b4 + a1(x)b3 + a2(x)b2 + a3(x)b1
//   c3 = a3 + b3 + a1(x)b2 + a2(x)b1 ; c2 = a2 + b2 + a1(x)b1 ; c1 = a1 + b1
__device__ __forceinline__ void fold_lds(SigRegs& A, const float* __restrict__ R,
                                         const float4* __restrict__ q4,
                                         int i_idx, int j_idx, int k0, int t) {
  const float4 b1lo = *(const float4*)(R + S1OFF);
  const float4 b1hi = *(const float4*)(R + S1OFF + 4);
  const float b1i = R[S1OFF + i_idx];
  const float b1j = R[S1OFF + j_idx];
  const float2 b1k = *(const float2*)(R + S1OFF + k0);
  const float b2own = R[S2OFF + (t >> 2)];
  const float2 b2p = *(const float2*)(R + S2OFF + ((2 * t) & 63));
  const float2 b3p = *(const float2*)(R + s3off(t >> 1) + 2 * (t & 1));
  const float4* q2 = (const float4*)(R + S2OFF + 16 * (t & 3));
#pragma unroll
  for (int r = 0; r < 4; ++r) {
    const float4 v2 = q2[r];
    const float4 v3 = *(const float4*)(R + s3off(4 * (t & 31) + r));
    const float4 v4 = q4[r];
    const float a3v = (r < 2) ? A.a30 : A.a31;   // e<8 -> a30
    const float4 bb = (r & 1) ? b1hi : b1lo;     // b1v[(4r+c)&7]
    A.s4[4 * r + 0] += v4.x + A.a1 * v3.x + A.a2 * v2.x + a3v * bb.x;
    A.s4[4 * r + 1] += v4.y + A.a1 * v3.y + A.a2 * v2.y + a3v * bb.y;
    A.s4[4 * r + 2] += v4.z + A.a1 * v3.z + A.a2 * v2.z + a3v * bb.z;
    A.s4[4 * r + 3] += v4.w + A.a1 * v3.w + A.a2 * v2.w + a3v * bb.w;
  }
  A.a30 += b3p.x + A.a1 * b2p.x + A.a2 * b1k.x;
  A.a31 += b3p.y + A.a1 * b2p.y + A.a2 * b1k.y;
  A.a2 += b2own + A.a1 * b1j;
  A.a1 += b1i;
}

__device__ __forceinline__ void loadq4(float4* dst, const float* __restrict__ gbase,
                                       int m, int t) {
  const float4* g = (const float4*)(gbase + (long)m * SIGLEN + S4OFF + 16 * t);
#pragma unroll
  for (int r = 0; r < 4; ++r) dst[r] = g[r];
}

// ------------------------- kernel 1: chunk signatures -------------------------
__global__ __launch_bounds__(256, 1) void sig_chunk(const float* __restrict__ path,
                                                    float* __restrict__ partials,
                                                    int nInc) {
  __shared__ float4 pl[(MAXLEN + 1) * 2];
  __shared__ float4 dv[MAXLEN * 2];
  const int t = threadIdx.x;
  const int c = blockIdx.x;
  const int i_idx = t >> 5;
  const int j_idx = (t >> 2) & 7;
  const int k0 = 2 * (t & 3);

  const long start = ((long)c * nInc) / NCHUNK;
  const long end = ((long)(c + 1) * nInc) / NCHUNK;
  const int len = (int)(end - start);

  const float4* gp = (const float4*)(path + start * 8);
  for (int idx = t; idx < (len + 1) * 2; idx += 256) pl[idx] = gp[idx];
  __syncthreads();
  for (int idx = t; idx < len * 2; idx += 256) {
    float4 a = pl[idx + 2], b = pl[idx];
    dv[idx] = make_float4(a.x - b.x, a.y - b.y, a.z - b.z, a.w - b.w);
  }
  __syncthreads();
  const float* dvf = (const float*)dv;

  SigRegs A;
#pragma unroll
  for (int e = 0; e < 16; ++e) A.s4[e] = 0.f;
  A.a1 = 0.f; A.a2 = 0.f; A.a30 = 0.f; A.a31 = 0.f;

  for (int it = 0; it < len; ++it) {
    const float4 d0 = dv[it * 2], d1 = dv[it * 2 + 1];
    const float dxl[8] = {d0.x, d0.y, d0.z, d0.w, d1.x, d1.y, d1.z, d1.w};
    const float dxi = dvf[it * 8 + i_idx];
    const float dxj = dvf[it * 8 + j_idx];
    const float2 dkk = *(const float2*)(dvf + it * 8 + k0);

    const float inner = 0.5f * A.a2 + dxj * ((1.f / 6.f) * A.a1 + (1.f / 24.f) * dxi);
    const float c0 = A.a30 + dkk.x * inner;
    const float c1 = A.a31 + dkk.y * inner;
#pragma unroll
    for (int l = 0; l < 8; ++l) A.s4[l] += c0 * dxl[l];
#pragma unroll
    for (int l = 0; l < 8; ++l) A.s4[8 + l] += c1 * dxl[l];
    const float common3 = A.a2 + dxj * (0.5f * A.a1 + (1.f / 6.f) * dxi);
    A.a30 += common3 * dkk.x;
    A.a31 += common3 * dkk.y;
    A.a2 += dxj * (A.a1 + 0.5f * dxi);
    A.a1 += dxi;
  }

  store_sig(A, partials + (long)c * SIGLEN, i_idx, t);
}

// ------- kernel 2: 1024 threads = 4 engines; fold all 64 partials -> out -------
__global__ __launch_bounds__(1024, 1) void sig_fold_merged(const float* __restrict__ partials,
                                                           float* __restrict__ g2,
                                                           float* __restrict__ out) {
  __shared__ float lsig[NCHUNK * LROW];  // 151552 B
  const int t = threadIdx.x;
  const int e = t >> 8;    // engine 0..3
  const int tl = t & 255;  // lane within engine
  const int i_idx = tl >> 5;
  const int j_idx = (tl >> 2) & 7;
  const int k0 = 2 * (tl & 3);

  const float* gbase = partials + (long)(16 * e) * SIGLEN;

  // Issue A/q4 loads first (needed first after the barrier).
  SigRegs A;
  load_sig(A, gbase, i_idx, tl);
  float4 qA[4], qB[4];
  loadq4(qA, gbase, 1, tl);
  loadq4(qB, gbase, 2, tl);

  // Stage all 64 sigs' lower levels (64*146 = 9344 float4 chunks) into LDS
  // rows 0..63: static 10-slot batch (issue all loads, then all LDS writes).
  {
    float4 vals[10];
#pragma unroll
    for (int s = 0; s < 10; ++s) {
      const int v = t + 1024 * s;
      const int vc = (v < NCHUNK * 146) ? v : (NCHUNK * 146 - 1);
      const int sig = vc / 146;
      const int r = vc - sig * 146;
      vals[s] = *(const float4*)(partials + (long)sig * SIGLEN + 4 * r);
    }
#pragma unroll
    for (int s = 0; s < 10; ++s) {
      const int v = t + 1024 * s;
      if (v < NCHUNK * 146) {
        const int sig = v / 146;
        const int r = v - sig * 146;
        const int off = (r < 18) ? 4 * r : s3off(r - 18);
        *(float4*)(lsig + sig * LROW + off) = vals[s];
      }
    }
  }
  __syncthreads();  // staging complete

  // Each engine: 15 folds over its group (runtime loop, 2-deep double-buffer).
#pragma unroll 1
  for (int m = 1; m + 2 < 16; m += 2) {  // m = 1,3,...,13 (14 folds)
    fold_lds(A, lsig + (16 * e + m) * LROW, qA, i_idx, j_idx, k0, tl);
    loadq4(qA, gbase, m + 2, tl);
    fold_lds(A, lsig + (16 * e + m + 1) * LROW, qB, i_idx, j_idx, k0, tl);
    if (m + 3 < 16) loadq4(qB, gbase, m + 3, tl);
  }
  fold_lds(A, lsig + (16 * e + 15) * LROW, qA, i_idx, j_idx, k0, tl);  // fold 15

  // Engines 1..3 publish results (same-CU: visible via L1/L2 after barrier's
  // vmcnt drain — no device fence needed inside one workgroup).
  if (e != 0) store_sig(A, g2 + (long)e * SIGLEN, i_idx, tl);
  __syncthreads();

  // Stage g2 sigs 1..3 lower levels into rows 0..2 (rows are free: all fold
  // reads finished before the barrier). 3*146 = 438 chunks, one per thread.
  if (t < 3 * 146) {
    const int sig = t / 146;
    const int r = t - sig * 146;
    const float4 val = *(const float4*)(g2 + (long)(sig + 1) * SIGLEN + 4 * r);
    const int off = (r < 18) ? 4 * r : s3off(r - 18);
    *(float4*)(lsig + sig * LROW + off) = val;
  }
  __syncthreads();

  // Engine 0: fold the 3 group results, store final signature.
  if (e == 0) {
    const float* g2b = g2 + SIGLEN;
    loadq4(qA, g2b, 0, tl);
    loadq4(qB, g2b, 1, tl);
    fold_lds(A, lsig + 0 * LROW, qA, i_idx, j_idx, k0, tl);
    loadq4(qA, g2b, 2, tl);
    fold_lds(A, lsig + 1 * LROW, qB, i_idx, j_idx, k0, tl);
    fold_lds(A, lsig + 2 * LROW, qA, i_idx, j_idx, k0, tl);
    store_sig(A, out, i_idx, tl);
  }
}

extern "C" void kernel_launch(void* const* d_in, const int* in_sizes, int n_in,
                              void* d_out, int out_size, void* d_ws, size_t ws_size,
                              hipStream_t stream) {
  const float* path = (const float*)d_in[0];
  float* out = (float*)d_out;
  const int L = in_sizes[0] / 8;
  const int nInc = L - 1;

  float* partials = (float*)d_ws;                  // NCHUNK * SIGLEN floats
  float* g2 = partials + (long)NCHUNK * SIGLEN;    // 4 * SIGLEN floats

  sig_chunk<<<NCHUNK, 256, 0, stream>>>(path, partials, nInc);
  sig_fold_merged<<<1, 1024, 0, stream>>>(partials, g2, out);
}

// Round 13
// 40.704 us; speedup vs baseline: 3.6220x; 3.6220x over previous
//
#include <hip/hip_runtime.h>

// Path signature, depth 4, D=8. Output layout (matches JAX flatten):
//   s1[8] | s2[64] (i*8+j) | s3[512] (i*64+j*8+k) | s4[4096] (i*512+j*64+k*8+l)
//
// TWO kernels, ONE dependency edge (rounds 7-11: 3-kernel trees pinned at
// ~28.4us regardless of fold count => ~8us/edge fixed cost dominates):
//   k1: 32 blocks x 256 thr, each computes the signature of its ~256-increment
//       chunk (state fully thread-private in registers, barrier-free scan).
//   k2: ONE block x 512 thr = 2 independent 256-thread fold engines.
//       All 32 partials' lower levels staged into 76KB LDS once; engine e
//       reg-accumulates sigs [16e,16e+16) (15 folds; engines concurrent on
//       the CU's 8 wave slots); engine 1 stores its product to g2 (same-CU L1,
//       visible after __syncthreads); engine 0 restages g2's lower levels into
//       a spare LDS row, folds it (16th serial fold), stores d_out.
// CRITICAL (round-12 lesson): merged block MUST pin the register budget —
// __launch_bounds__(1024,1) let the allocator pick VGPR=64 => fold live-set
// (~120) spilled to scratch => 147us (VALUBusy 0.0004%). Here
// __launch_bounds__(512, 2) => 2 waves/EU => VGPR cap 256. k2 live-set ~120.
#define SIGLEN 4680
#define S1OFF 0
#define S2OFF 8
#define S3OFF 72
#define S4OFF 584
#define NCHUNK 32
#define MAXLEN 256
#define LROW 592  // LDS floats per staged sig (584 + 8 pad)

struct SigRegs { float s4[16]; float a1, a2, a30, a31; };

// s3 chunk swizzle: float4 chunk c (0..127) lives at float-offset
// S3OFF + 4*(c ^ ((c>>4)&7)). Involution, bijective, 16B-aligned. Makes the
// 16*(t&31)-pattern b128 reads 4-way instead of 16-way conflicted.
__device__ __forceinline__ int s3off(int c) {
  return S3OFF + 4 * (c ^ ((c >> 4) & 7));
}

__device__ __forceinline__ void load_sig(SigRegs& A, const float* __restrict__ B,
                                         int i_idx, int t) {
  const float4* p4 = (const float4*)(B + S4OFF + 16 * t);
#pragma unroll
  for (int r = 0; r < 4; ++r) {
    const float4 v = p4[r];
    A.s4[4 * r] = v.x; A.s4[4 * r + 1] = v.y; A.s4[4 * r + 2] = v.z; A.s4[4 * r + 3] = v.w;
  }
  A.a1 = B[S1OFF + i_idx];
  A.a2 = B[S2OFF + (t >> 2)];
  const float2 a3i = *(const float2*)(B + S3OFF + 2 * t);
  A.a30 = a3i.x; A.a31 = a3i.y;
}

__device__ __forceinline__ void store_sig(const SigRegs& A, float* __restrict__ o,
                                          int i_idx, int t) {
  if ((t & 31) == 0) o[S1OFF + i_idx] = A.a1;
  if ((t & 3) == 0) o[S2OFF + (t >> 2)] = A.a2;
  *(float2*)(o + S3OFF + 2 * t) = make_float2(A.a30, A.a31);
  float4* o4 = (float4*)(o + S4OFF + 16 * t);
#pragma unroll
  for (int r = 0; r < 4; ++r)
    o4[r] = make_float4(A.s4[4 * r], A.s4[4 * r + 1], A.s4[4 * r + 2], A.s4[4 * r + 3]);
}

// Chen left-fold A <- A*B; B lower levels from LDS row R, B.s4 own-slice from
// registers q4. Math identical to the verified round-2 kernel:
//   c4 = a4 + b4 + a1(x)b3 + a2(x)b2 + a3(x)b1
//   c3 = a3 + b3 + a1(x)b2 + a2(x)b1 ; c2 = a2 + b2 + a1(x)b1 ; c1 = a1 + b1
__device__ __forceinline__ void fold_lds(SigRegs& A, const float* __restrict__ R,
                                         const float4* __restrict__ q4,
                                         int i_idx, int j_idx, int k0, int t) {
  const float4 b1lo = *(const float4*)(R + S1OFF);
  const float4 b1hi = *(const float4*)(R + S1OFF + 4);
  const float b1i = R[S1OFF + i_idx];
  const float b1j = R[S1OFF + j_idx];
  const float2 b1k = *(const float2*)(R + S1OFF + k0);
  const float b2own = R[S2OFF + (t >> 2)];
  const float2 b2p = *(const float2*)(R + S2OFF + ((2 * t) & 63));
  const float2 b3p = *(const float2*)(R + s3off(t >> 1) + 2 * (t & 1));
  const float4* q2 = (const float4*)(R + S2OFF + 16 * (t & 3));
#pragma unroll
  for (int r = 0; r < 4; ++r) {
    const float4 v2 = q2[r];
    const float4 v3 = *(const float4*)(R + s3off(4 * (t & 31) + r));
    const float4 v4 = q4[r];
    const float a3v = (r < 2) ? A.a30 : A.a31;   // e<8 -> a30
    const float4 bb = (r & 1) ? b1hi : b1lo;     // b1v[(4r+c)&7]
    A.s4[4 * r + 0] += v4.x + A.a1 * v3.x + A.a2 * v2.x + a3v * bb.x;
    A.s4[4 * r + 1] += v4.y + A.a1 * v3.y + A.a2 * v2.y + a3v * bb.y;
    A.s4[4 * r + 2] += v4.z + A.a1 * v3.z + A.a2 * v2.z + a3v * bb.z;
    A.s4[4 * r + 3] += v4.w + A.a1 * v3.w + A.a2 * v2.w + a3v * bb.w;
  }
  A.a30 += b3p.x + A.a1 * b2p.x + A.a2 * b1k.x;
  A.a31 += b3p.y + A.a1 * b2p.y + A.a2 * b1k.y;
  A.a2 += b2own + A.a1 * b1j;
  A.a1 += b1i;
}

__device__ __forceinline__ void loadq4(float4* dst, const float* __restrict__ gbase,
                                       int m, int t) {
  const float4* g = (const float4*)(gbase + (long)m * SIGLEN + S4OFF + 16 * t);
#pragma unroll
  for (int r = 0; r < 4; ++r) dst[r] = g[r];
}

// ------------------------- kernel 1: chunk signatures -------------------------
__global__ __launch_bounds__(256, 1) void sig_chunk(const float* __restrict__ path,
                                                    float* __restrict__ partials,
                                                    int nInc) {
  __shared__ float4 pl[(MAXLEN + 1) * 2];
  __shared__ float4 dv[MAXLEN * 2];
  const int t = threadIdx.x;
  const int c = blockIdx.x;
  const int i_idx = t >> 5;
  const int j_idx = (t >> 2) & 7;
  const int k0 = 2 * (t & 3);

  const long start = ((long)c * nInc) / NCHUNK;
  const long end = ((long)(c + 1) * nInc) / NCHUNK;
  const int len = (int)(end - start);

  const float4* gp = (const float4*)(path + start * 8);
  for (int idx = t; idx < (len + 1) * 2; idx += 256) pl[idx] = gp[idx];
  __syncthreads();
  for (int idx = t; idx < len * 2; idx += 256) {
    float4 a = pl[idx + 2], b = pl[idx];
    dv[idx] = make_float4(a.x - b.x, a.y - b.y, a.z - b.z, a.w - b.w);
  }
  __syncthreads();
  const float* dvf = (const float*)dv;

  SigRegs A;
#pragma unroll
  for (int e = 0; e < 16; ++e) A.s4[e] = 0.f;
  A.a1 = 0.f; A.a2 = 0.f; A.a30 = 0.f; A.a31 = 0.f;

  for (int it = 0; it < len; ++it) {
    const float4 d0 = dv[it * 2], d1 = dv[it * 2 + 1];
    const float dxl[8] = {d0.x, d0.y, d0.z, d0.w, d1.x, d1.y, d1.z, d1.w};
    const float dxi = dvf[it * 8 + i_idx];
    const float dxj = dvf[it * 8 + j_idx];
    const float2 dkk = *(const float2*)(dvf + it * 8 + k0);

    const float inner = 0.5f * A.a2 + dxj * ((1.f / 6.f) * A.a1 + (1.f / 24.f) * dxi);
    const float c0 = A.a30 + dkk.x * inner;
    const float c1 = A.a31 + dkk.y * inner;
#pragma unroll
    for (int l = 0; l < 8; ++l) A.s4[l] += c0 * dxl[l];
#pragma unroll
    for (int l = 0; l < 8; ++l) A.s4[8 + l] += c1 * dxl[l];
    const float common3 = A.a2 + dxj * (0.5f * A.a1 + (1.f / 6.f) * dxi);
    A.a30 += common3 * dkk.x;
    A.a31 += common3 * dkk.y;
    A.a2 += dxj * (A.a1 + 0.5f * dxi);
    A.a1 += dxi;
  }

  store_sig(A, partials + (long)c * SIGLEN, i_idx, t);
}

// ------ kernel 2: 512 threads = 2 engines; fold all 32 partials -> out ------
__global__ __launch_bounds__(512, 2) void sig_fold2(const float* __restrict__ partials,
                                                    float* __restrict__ g2,
                                                    float* __restrict__ out) {
  __shared__ float lsig[(NCHUNK + 1) * LROW];  // 33 rows = 78144 B
  const int t = threadIdx.x;
  const int e = t >> 8;    // engine 0 or 1
  const int tl = t & 255;  // lane within engine
  const int i_idx = tl >> 5;
  const int j_idx = (tl >> 2) & 7;
  const int k0 = 2 * (tl & 3);

  const float* gbase = partials + (long)(16 * e) * SIGLEN;

  // Issue A/q4 loads first (needed right after the staging barrier).
  SigRegs A;
  load_sig(A, gbase, i_idx, tl);
  float4 qA[4], qB[4];
  loadq4(qA, gbase, 1, tl);
  loadq4(qB, gbase, 2, tl);

  // Stage all 32 sigs' lower levels (32*146 = 4672 float4 chunks) into LDS
  // rows 0..31: static 10-slot batch (issue all loads, then all LDS writes).
  {
    float4 vals[10];
#pragma unroll
    for (int s = 0; s < 10; ++s) {
      const int v = t + 512 * s;
      const int vc = (v < NCHUNK * 146) ? v : (NCHUNK * 146 - 1);
      const int sig = vc / 146;
      const int r = vc - sig * 146;
      vals[s] = *(const float4*)(partials + (long)sig * SIGLEN + 4 * r);
    }
#pragma unroll
    for (int s = 0; s < 10; ++s) {
      const int v = t + 512 * s;
      if (v < NCHUNK * 146) {
        const int sig = v / 146;
        const int r = v - sig * 146;
        const int off = (r < 18) ? 4 * r : s3off(r - 18);
        *(float4*)(lsig + sig * LROW + off) = vals[s];
      }
    }
  }
  __syncthreads();  // staging complete

  // Each engine: 15 folds over its group (runtime loop, 2-deep double-buffer;
  // live-set control — full unroll / deep rings spilled in rounds 4-5).
#pragma unroll 1
  for (int m = 1; m + 2 < 16; m += 2) {  // m = 1,3,...,13 (14 folds)
    fold_lds(A, lsig + (16 * e + m) * LROW, qA, i_idx, j_idx, k0, tl);
    loadq4(qA, gbase, m + 2, tl);
    fold_lds(A, lsig + (16 * e + m + 1) * LROW, qB, i_idx, j_idx, k0, tl);
    if (m + 3 < 16) loadq4(qB, gbase, m + 3, tl);
  }
  fold_lds(A, lsig + (16 * e + 15) * LROW, qA, i_idx, j_idx, k0, tl);  // fold 15

  // Engine 1 publishes its product (same CU => same L1; __syncthreads drains
  // vmcnt and orders stores before engine 0's loads — no device fence needed).
  if (e == 1) store_sig(A, g2, i_idx, tl);
  __syncthreads();

  // Engine 0 threads 0..145: restage g2's lower levels into spare row 32.
  if (t < 146) {
    const int r = t;
    const float4 val = *(const float4*)(g2 + 4 * r);
    const int off = (r < 18) ? 4 * r : s3off(r - 18);
    *(float4*)(lsig + NCHUNK * LROW + off) = val;
  }
  if (e == 0) loadq4(qA, g2, 0, tl);  // g2's s4 slice (L1-resident)
  __syncthreads();  // restage visible

  if (e == 0) {
    fold_lds(A, lsig + NCHUNK * LROW, qA, i_idx, j_idx, k0, tl);  // 16th fold
    store_sig(A, out, i_idx, tl);
  }
}

extern "C" void kernel_launch(void* const* d_in, const int* in_sizes, int n_in,
                              void* d_out, int out_size, void* d_ws, size_t ws_size,
                              hipStream_t stream) {
  const float* path = (const float*)d_in[0];
  float* out = (float*)d_out;
  const int L = in_sizes[0] / 8;
  const int nInc = L - 1;

  float* partials = (float*)d_ws;                  // NCHUNK * SIGLEN floats
  float* g2 = partials + (long)NCHUNK * SIGLEN;    // SIGLEN floats

  sig_chunk<<<NCHUNK, 256, 0, stream>>>(path, partials, nInc);
  sig_fold2<<<1, 512, 0, stream>>>(partials, g2, out);
}

// Round 14
// 28.270 us; speedup vs baseline: 5.2150x; 1.4398x over previous
//
#include <hip/hip_runtime.h>

// Path signature, depth 4, D=8. Output layout (matches JAX flatten):
//   s1[8] | s2[64] (i*8+j) | s3[512] (i*64+j*8+k) | s4[4096] (i*512+j*64+k*8+l)
//
// BEST-MEASURED CONFIG (round 11, 28.36us): three kernels, 8x8 tree.
// Session cost model (rounds 7-13): total ~= 18-20us fixed (3 dispatches +
// 2 AQL dependency edges under graph replay) + ~7us exec. Fold ~0.2us each
// (R7's 30 serial folds == R11's 14 at 28.4). All structural alternatives
// measured WORSE: 1-kernel fused w/ flags 37.5 (R6), 2-kernel flag handoff
// 34.3 (R9), 2-kernel serial-63-fold 49.2 (R10), 2-kernel same-CU twin
// engines 40.7 (R13, LDS-port serialization), 1024-thr merge 147 (R12,
// VGPR=64 spill). Do not re-derive without new evidence.
//   k1: 64 blocks, each computes the signature of its ~128-increment chunk
//       (state fully thread-private in registers, barrier-free scan)
//   k2: 8 blocks, each folds 8 chunk sigs (Chen product, LDS-staged B)
//   k3: 1 block, folds the 8 group sigs into d_out
// Fold engine (validated rounds 6-11): B lower levels (s1..s3) staged in LDS
// once per fold phase (one static batch); B.s4 own-slice via 2-deep register
// double-buffer. Fold loop NOT unrolled (live-set control; 4-deep ring + full
// unroll spilled in round 4: VGPR=256, +10MB scratch writes, 3x slower).
#define SIGLEN 4680
#define S1OFF 0
#define S2OFF 8
#define S3OFF 72
#define S4OFF 584
#define NCHUNK 64
#define NG 8
#define MAXLEN 128
#define LROW 592  // LDS floats per staged sig (584 + 8 pad)

struct SigRegs { float s4[16]; float a1, a2, a30, a31; };

// s3 chunk swizzle: float4 chunk c (0..127) lives at float-offset
// S3OFF + 4*(c ^ ((c>>4)&7)). Involution, bijective, 16B-aligned. Makes the
// 16*(t&31)-pattern b128 reads 4-way instead of 16-way conflicted.
__device__ __forceinline__ int s3off(int c) {
  return S3OFF + 4 * (c ^ ((c >> 4) & 7));
}

__device__ __forceinline__ void load_sig(SigRegs& A, const float* __restrict__ B,
                                         int i_idx, int t) {
  const float4* p4 = (const float4*)(B + S4OFF + 16 * t);
#pragma unroll
  for (int r = 0; r < 4; ++r) {
    const float4 v = p4[r];
    A.s4[4 * r] = v.x; A.s4[4 * r + 1] = v.y; A.s4[4 * r + 2] = v.z; A.s4[4 * r + 3] = v.w;
  }
  A.a1 = B[S1OFF + i_idx];
  A.a2 = B[S2OFF + (t >> 2)];
  const float2 a3i = *(const float2*)(B + S3OFF + 2 * t);
  A.a30 = a3i.x; A.a31 = a3i.y;
}

__device__ __forceinline__ void store_sig(const SigRegs& A, float* __restrict__ o,
                                          int i_idx, int t) {
  if ((t & 31) == 0) o[S1OFF + i_idx] = A.a1;
  if ((t & 3) == 0) o[S2OFF + (t >> 2)] = A.a2;
  *(float2*)(o + S3OFF + 2 * t) = make_float2(A.a30, A.a31);
  float4* o4 = (float4*)(o + S4OFF + 16 * t);
#pragma unroll
  for (int r = 0; r < 4; ++r)
    o4[r] = make_float4(A.s4[4 * r], A.s4[4 * r + 1], A.s4[4 * r + 2], A.s4[4 * r + 3]);
}

// Chen left-fold A <- A*B; B lower levels from LDS row R, B.s4 own-slice from
// registers q4. Math identical to the verified round-2 kernel:
//   c4 = a4 + b4 + a1(x)b3 + a2(x)b2 + a3(x)b1
//   c3 = a3 + b3 + a1(x)b2 + a2(x)b1 ; c2 = a2 + b2 + a1(x)b1 ; c1 = a1 + b1
__device__ __forceinline__ void fold_lds(SigRegs& A, const float* __restrict__ R,
                                         const float4* __restrict__ q4,
                                         int i_idx, int j_idx, int k0, int t) {
  const float4 b1lo = *(const float4*)(R + S1OFF);
  const float4 b1hi = *(const float4*)(R + S1OFF + 4);
  const float b1i = R[S1OFF + i_idx];
  const float b1j = R[S1OFF + j_idx];
  const float2 b1k = *(const float2*)(R + S1OFF + k0);
  const float b2own = R[S2OFF + (t >> 2)];
  const float2 b2p = *(const float2*)(R + S2OFF + ((2 * t) & 63));
  const float2 b3p = *(const float2*)(R + s3off(t >> 1) + 2 * (t & 1));
  const float4* q2 = (const float4*)(R + S2OFF + 16 * (t & 3));
#pragma unroll
  for (int r = 0; r < 4; ++r) {
    const float4 v2 = q2[r];
    const float4 v3 = *(const float4*)(R + s3off(4 * (t & 31) + r));
    const float4 v4 = q4[r];
    const float a3v = (r < 2) ? A.a30 : A.a31;   // e<8 -> a30
    const float4 bb = (r & 1) ? b1hi : b1lo;     // b1v[(4r+c)&7]
    A.s4[4 * r + 0] += v4.x + A.a1 * v3.x + A.a2 * v2.x + a3v * bb.x;
    A.s4[4 * r + 1] += v4.y + A.a1 * v3.y + A.a2 * v2.y + a3v * bb.y;
    A.s4[4 * r + 2] += v4.z + A.a1 * v3.z + A.a2 * v2.z + a3v * bb.z;
    A.s4[4 * r + 3] += v4.w + A.a1 * v3.w + A.a2 * v2.w + a3v * bb.w;
  }
  A.a30 += b3p.x + A.a1 * b2p.x + A.a2 * b1k.x;
  A.a31 += b3p.y + A.a1 * b2p.y + A.a2 * b1k.y;
  A.a2 += b2own + A.a1 * b1j;
  A.a1 += b1i;
}

__device__ __forceinline__ void loadq4(float4* dst, const float* __restrict__ gbase,
                                       int m, int t) {
  const float4* g = (const float4*)(gbase + (long)m * SIGLEN + S4OFF + 16 * t);
#pragma unroll
  for (int r = 0; r < 4; ++r) dst[r] = g[r];
}

// Fold sigs gbase[0..NG-1] -> outp. NG = 8: stage rows 0..7 (row 0 unused),
// then 7 folds (sigs 1..7) with a 2-deep q4 double-buffer.
__device__ __forceinline__ void fold8(const float* __restrict__ gbase,
                                      float* __restrict__ outp,
                                      float* __restrict__ lsig,
                                      int i_idx, int j_idx, int k0, int t) {
  // Stage lower levels (146 float4 chunks x NG sigs = 1168) into LDS.
  // Static 5-slot batch (issue all loads, then all LDS writes); s3 swizzled.
  float4 vals[5];
#pragma unroll
  for (int s = 0; s < 5; ++s) {
    const int v = t + 256 * s;
    const int vc = (v < NG * 146) ? v : (NG * 146 - 1);
    const int sig = vc / 146;
    const int r = vc - sig * 146;
    vals[s] = *(const float4*)(gbase + (long)sig * SIGLEN + 4 * r);
  }

  SigRegs A;
  load_sig(A, gbase, i_idx, t);  // A = sig 0
  float4 qA[4], qB[4];
  loadq4(qA, gbase, 1, t);
  loadq4(qB, gbase, 2, t);

#pragma unroll
  for (int s = 0; s < 5; ++s) {
    const int v = t + 256 * s;
    if (v < NG * 146) {
      const int sig = v / 146;
      const int r = v - sig * 146;
      const int off = (r < 18) ? 4 * r : s3off(r - 18);
      *(float4*)(lsig + sig * LROW + off) = vals[s];
    }
  }
  __syncthreads();  // LDS staging complete

  // Folds 1..7: runtime loop, 2-wide software pipeline, named double-buffer.
#pragma unroll 1
  for (int m = 1; m + 2 < NG; m += 2) {  // m = 1, 3, 5 (6 folds)
    fold_lds(A, lsig + m * LROW, qA, i_idx, j_idx, k0, t);
    loadq4(qA, gbase, m + 2, t);
    fold_lds(A, lsig + (m + 1) * LROW, qB, i_idx, j_idx, k0, t);
    if (m + 3 < NG) loadq4(qB, gbase, m + 3, t);
  }
  fold_lds(A, lsig + (NG - 1) * LROW, qA, i_idx, j_idx, k0, t);  // fold 7
  store_sig(A, outp, i_idx, t);
}

// ------------------------- kernel 1: chunk signatures -------------------------
__global__ __launch_bounds__(256, 1) void sig_chunk(const float* __restrict__ path,
                                                    float* __restrict__ partials,
                                                    int nInc) {
  __shared__ float4 pl[(MAXLEN + 1) * 2];
  __shared__ float4 dv[MAXLEN * 2];
  const int t = threadIdx.x;
  const int c = blockIdx.x;
  const int i_idx = t >> 5;
  const int j_idx = (t >> 2) & 7;
  const int k0 = 2 * (t & 3);

  const long start = ((long)c * nInc) / NCHUNK;
  const long end = ((long)(c + 1) * nInc) / NCHUNK;
  const int len = (int)(end - start);

  const float4* gp = (const float4*)(path + start * 8);
  for (int idx = t; idx < (len + 1) * 2; idx += 256) pl[idx] = gp[idx];
  __syncthreads();
  for (int idx = t; idx < len * 2; idx += 256) {
    float4 a = pl[idx + 2], b = pl[idx];
    dv[idx] = make_float4(a.x - b.x, a.y - b.y, a.z - b.z, a.w - b.w);
  }
  __syncthreads();
  const float* dvf = (const float*)dv;

  SigRegs A;
#pragma unroll
  for (int e = 0; e < 16; ++e) A.s4[e] = 0.f;
  A.a1 = 0.f; A.a2 = 0.f; A.a30 = 0.f; A.a31 = 0.f;

  for (int it = 0; it < len; ++it) {
    const float4 d0 = dv[it * 2], d1 = dv[it * 2 + 1];
    const float dxl[8] = {d0.x, d0.y, d0.z, d0.w, d1.x, d1.y, d1.z, d1.w};
    const float dxi = dvf[it * 8 + i_idx];
    const float dxj = dvf[it * 8 + j_idx];
    const float2 dkk = *(const float2*)(dvf + it * 8 + k0);

    const float inner = 0.5f * A.a2 + dxj * ((1.f / 6.f) * A.a1 + (1.f / 24.f) * dxi);
    const float c0 = A.a30 + dkk.x * inner;
    const float c1 = A.a31 + dkk.y * inner;
#pragma unroll
    for (int l = 0; l < 8; ++l) A.s4[l] += c0 * dxl[l];
#pragma unroll
    for (int l = 0; l < 8; ++l) A.s4[8 + l] += c1 * dxl[l];
    const float common3 = A.a2 + dxj * (0.5f * A.a1 + (1.f / 6.f) * dxi);
    A.a30 += common3 * dkk.x;
    A.a31 += common3 * dkk.y;
    A.a2 += dxj * (A.a1 + 0.5f * dxi);
    A.a1 += dxi;
  }

  store_sig(A, partials + (long)c * SIGLEN, i_idx, t);
}

// ------------------- kernel 2: fold 8 chunk sigs per block -------------------
__global__ __launch_bounds__(256, 1) void sig_fold8(const float* __restrict__ in,
                                                    float* __restrict__ outp) {
  __shared__ float lsig[NG * LROW];  // 18944 B
  const int t = threadIdx.x;
  const int b = blockIdx.x;
  const int i_idx = t >> 5;
  const int j_idx = (t >> 2) & 7;
  const int k0 = 2 * (t & 3);
  fold8(in + (long)(NG * b) * SIGLEN, outp + (long)b * SIGLEN, lsig,
        i_idx, j_idx, k0, t);
}

// ---------------------- kernel 3: final fold of 8 sigs ----------------------
__global__ __launch_bounds__(256, 1) void sig_fold_final(const float* __restrict__ in,
                                                         float* __restrict__ outp) {
  __shared__ float lsig[NG * LROW];
  const int t = threadIdx.x;
  const int i_idx = t >> 5;
  const int j_idx = (t >> 2) & 7;
  const int k0 = 2 * (t & 3);
  fold8(in, outp, lsig, i_idx, j_idx, k0, t);
}

extern "C" void kernel_launch(void* const* d_in, const int* in_sizes, int n_in,
                              void* d_out, int out_size, void* d_ws, size_t ws_size,
                              hipStream_t stream) {
  const float* path = (const float*)d_in[0];
  float* out = (float*)d_out;
  const int L = in_sizes[0] / 8;
  const int nInc = L - 1;

  float* partials = (float*)d_ws;                    // NCHUNK * SIGLEN floats
  float* g2 = partials + (long)NCHUNK * SIGLEN;      // NG * SIGLEN floats

  sig_chunk<<<NCHUNK, 256, 0, stream>>>(path, partials, nInc);
  sig_fold8<<<NG, 256, 0, stream>>>(partials, g2);
  sig_fold_final<<<1, 256, 0, stream>>>(g2, out);
}